// Round 5
// baseline (277.298 us; speedup 1.0000x reference)
//
#include <hip/hip_runtime.h>

#define N_TOK 4096
#define C_IN 256
#define CI_ 128
#define LOG2E 1.4426950408889634f

typedef unsigned short u16;
typedef unsigned int   u32;
typedef __attribute__((ext_vector_type(8))) short bf16x8;
typedef __attribute__((ext_vector_type(4))) float f32x4;

// ---- bf16 helpers ----
__device__ __forceinline__ float lo16f(u32 u){ union{u32 i; float f;} c; c.i = u << 16; return c.f; }
__device__ __forceinline__ float hi16f(u32 u){ union{u32 i; float f;} c; c.i = u & 0xffff0000u; return c.f; }
__device__ __forceinline__ void bf8f(const uint4 u, float* f){
    f[0]=lo16f(u.x); f[1]=hi16f(u.x); f[2]=lo16f(u.y); f[3]=hi16f(u.y);
    f[4]=lo16f(u.z); f[5]=hi16f(u.z); f[6]=lo16f(u.w); f[7]=hi16f(u.w);
}
__device__ __forceinline__ float bf1f(u16 v){ union{u32 i; float f;} c; c.i = ((u32)v)<<16; return c.f; }
__device__ __forceinline__ u16 f2bf(float f){
    union{float f; u32 i;} c; c.f = f;
    u32 i = c.i;
    u32 r = (i + 0x7fffu + ((i >> 16) & 1u)) >> 16;   // RNE
    return (u16)r;
}
__device__ __forceinline__ u32 packbf(float a, float b){
    return (u32)f2bf(a) | ((u32)f2bf(b) << 16);
}

__device__ __forceinline__ void load8(const void* base, size_t idx, int flag, float* f){
    if (flag) {
        const float* p = (const float*)base + idx;
        *(float4*)&f[0] = *(const float4*)p;
        *(float4*)&f[4] = *(const float4*)(p + 4);
    } else {
        uint4 u = *(const uint4*)((const u16*)base + idx);
        bf8f(u, f);
    }
}
__device__ __forceinline__ void load4(const void* base, size_t idx, int flag, float* f){
    if (flag) {
        float4 v = *(const float4*)((const float*)base + idx);
        f[0]=v.x; f[1]=v.y; f[2]=v.z; f[3]=v.w;
    } else {
        uint2 u = *(const uint2*)((const u16*)base + idx);
        f[0]=lo16f(u.x); f[1]=hi16f(u.x); f[2]=lo16f(u.y); f[3]=hi16f(u.y);
    }
}

// ===================== dtype detect =====================
__global__ __launch_bounds__(64) void detect_kernel(const u16* __restrict__ wg, int* __restrict__ flag)
{
    int lane = threadIdx.x;
    int cnt = 0;
    for (int i = lane; i < 256; i += 64) {
        u16 v = wg[2 * i];
        if (((v >> 7) & 0xFF) >= 128) cnt++;
    }
    #pragma unroll
    for (int off = 32; off; off >>= 1) cnt += __shfl_down(cnt, off);
    if (lane == 0) *flag = (cnt >= 8) ? 1 : 0;
}

// ===================== param canonicalize (+stats zero) =====================
__global__ __launch_bounds__(256) void convert_params_kernel(
    const void* wg, const void* wt, const void* wp, const void* wo,
    const void* bg, const void* bt, const void* bp, const void* bo,
    const void* gm, const void* bt2,
    const int* __restrict__ flag, float* __restrict__ canon, u16* __restrict__ canon_bf,
    float* __restrict__ stats)
{
    int idx = blockIdx.x * 256 + threadIdx.x;
    if (idx >= 132224) {
        int j = idx - 132224;
        if (j < 512) stats[j] = 0.f;
        return;
    }
    int f = *flag;
    const void* src; int loc;
    if      (idx < 32768)  { src = wg;  loc = idx; }
    else if (idx < 65536)  { src = wt;  loc = idx - 32768; }
    else if (idx < 98304)  { src = wp;  loc = idx - 65536; }
    else if (idx < 131072) { src = wo;  loc = idx - 98304; }
    else if (idx < 131200) { src = bg;  loc = idx - 131072; }
    else if (idx < 131328) { src = bt;  loc = idx - 131200; }
    else if (idx < 131456) { src = bp;  loc = idx - 131328; }
    else if (idx < 131712) { src = bo;  loc = idx - 131456; }
    else if (idx < 131968) { src = gm;  loc = idx - 131712; }
    else                   { src = bt2; loc = idx - 131968; }
    float v = f ? ((const float*)src)[loc] : bf1f(((const u16*)src)[loc]);
    canon[idx] = v;
    if (idx < 131072) canon_bf[idx] = f2bf(v);
}

// =====================================================================
// Kernel A: MFMA projections, 8 waves, one-ahead x prefetch.
// wave w: r in [48w, 48w+48). n-tile 64. K=256, chunks of 32.
// =====================================================================
__global__ __launch_bounds__(512) void proj_kernel(
    const void* __restrict__ x, const float* __restrict__ canon,
    const u16* __restrict__ wbf, const int* __restrict__ flagp,
    u16* __restrict__ gbuf, u16* __restrict__ tbufT, u16* __restrict__ pbufT)
{
    __shared__ __align__(16) u16 plds[64 * 400];   // loop: [64][40]; epilogue: [64][400]
    const int flag = *flagp;
    const int b  = blockIdx.y;
    const int n0 = blockIdx.x * 64;
    const int tid = threadIdx.x;
    const int w    = tid >> 6;
    const int lane = tid & 63;
    const int col  = lane & 15;
    const int quad = lane >> 4;
    const int rw   = w * 48;

    f32x4 acc[3][4];
    #pragma unroll
    for (int i = 0; i < 3; ++i)
        #pragma unroll
        for (int j = 0; j < 4; ++j) acc[i][j] = (f32x4){0.f,0.f,0.f,0.f};

    const size_t xb = (size_t)b * C_IN * N_TOK;
    const int sk  = tid >> 4;          // k 0..31
    const int sn4 = (tid & 15) * 4;    // n base
    const int skk = sk ^ (((sn4 >> 3) & 3) << 3);

    float pre[4];
    load4(x, xb + (size_t)sk * N_TOK + n0 + sn4, flag, pre);

    for (int kc = 0; kc < 8; ++kc) {
        const int k0 = kc * 32;
        __syncthreads();
        #pragma unroll
        for (int i = 0; i < 4; ++i) plds[(sn4 + i) * 40 + skk] = f2bf(pre[i]);
        __syncthreads();
        if (kc < 7)
            load4(x, xb + (size_t)(k0 + 32 + sk) * N_TOK + n0 + sn4, flag, pre);
        bf16x8 bfr[4];
        #pragma unroll
        for (int nf = 0; nf < 4; ++nf) {
            int n = nf * 16 + col;
            int q2 = quad ^ ((n >> 3) & 3);
            bfr[nf] = *(const bf16x8*)&plds[n * 40 + q2 * 8];
        }
        #pragma unroll
        for (int rs = 0; rs < 3; ++rs) {
            bf16x8 afr = *(const bf16x8*)&wbf[(size_t)(rw + rs * 16 + col) * 256 + k0 + quad * 8];
            #pragma unroll
            for (int nf = 0; nf < 4; ++nf)
                acc[rs][nf] = __builtin_amdgcn_mfma_f32_16x16x32_bf16(afr, bfr[nf], acc[rs][nf], 0, 0, 0);
        }
    }

    // ---- bias + restage C to LDS cl[n][r] ----
    __syncthreads();
    #pragma unroll
    for (int rs = 0; rs < 3; ++rs) {
        int r0 = rw + rs * 16 + quad * 4;
        float b0 = canon[131072 + r0 + 0];
        float b1 = canon[131072 + r0 + 1];
        float b2 = canon[131072 + r0 + 2];
        float b3 = canon[131072 + r0 + 3];
        #pragma unroll
        for (int nf = 0; nf < 4; ++nf) {
            int n = nf * 16 + col;
            uint2 pv;
            pv.x = packbf(acc[rs][nf][0] + b0, acc[rs][nf][1] + b1);
            pv.y = packbf(acc[rs][nf][2] + b2, acc[rs][nf][3] + b3);
            *(uint2*)&plds[n * 400 + r0] = pv;
        }
    }
    __syncthreads();

    const size_t bN = (size_t)b * N_TOK;
    {   // gbuf [c][n]: r = tid&127, n-quarter = tid>>7
        int r = tid & 127, nq = tid >> 7;
        u16 tmp[16];
        #pragma unroll
        for (int j = 0; j < 16; ++j) tmp[j] = plds[(nq * 16 + j) * 400 + r];
        u16* dst = &gbuf[((size_t)b * CI_ + r) * N_TOK + n0 + nq * 16];
        *(uint4*)(dst + 0) = *(uint4*)&tmp[0];
        *(uint4*)(dst + 8) = *(uint4*)&tmp[8];
    }
    {   // tbufT / pbufT [n][c]: n = tid&63, part = tid>>6 (0..7)
        int n = tid & 63, part = tid >> 6;
        const u16* src = (part < 4) ? &plds[n * 400 + 128 + part * 32]
                                    : &plds[n * 400 + 256 + (part - 4) * 32];
        u16* dst = (part < 4) ? &tbufT[(bN + n0 + n) * CI_ + part * 32]
                              : &pbufT[(bN + n0 + n) * CI_ + (part - 4) * 32];
        #pragma unroll
        for (int v = 0; v < 4; ++v) *(uint4*)(dst + v * 8) = *(const uint4*)(src + v * 8);
    }
}

// =====================================================================
// Kernel B: MFMA flash attention + register-prefetch double buffer.
// LDS layout identical to R4. Softmax in exp2 domain, guarded rescale.
// =====================================================================
#define PH_OFF(p) ((p) * 16384)
#define G_OFF(p)  (32768 + (p) * 20480)
#define PB_OFF    73728
#define MST_OFF   90112
#define LST_OFF   90368
#define SMEM_SZ   90624

__global__ __launch_bounds__(512) void attn_kernel(
    const u16* __restrict__ tbufT, const u16* __restrict__ pbufT,
    const u16* __restrict__ gbuf, u16* __restrict__ ytb)
{
    __shared__ __align__(16) char smem[SMEM_SZ];
    const int b   = blockIdx.y;
    const int q0  = blockIdx.x * 64;
    const int tid = threadIdx.x;
    const int w    = tid >> 6;
    const int lane = tid & 63;
    const int col  = lane & 15;
    const int quad = lane >> 4;
    const int wq   = w & 3;
    const int ms   = w >> 2;
    const int qw   = wq * 16;

    bf16x8 thf[4];
    {
        const u16* tb = tbufT + ((size_t)b * N_TOK + q0 + qw + col) * CI_;
        #pragma unroll
        for (int kc = 0; kc < 4; ++kc)
            thf[kc] = *(const bf16x8*)(tb + kc * 32 + quad * 8);
    }

    f32x4 yacc[8];
    #pragma unroll
    for (int i = 0; i < 8; ++i) yacc[i] = (f32x4){0.f, 0.f, 0.f, 0.f};
    float m_st = -3.0e38f, l_st = 0.f;

    const size_t bN = (size_t)b * N_TOK;
    const size_t bC = (size_t)b * CI_;

    // staging source indices (fixed per thread)
    const int sm  = tid >> 4, sh  = tid & 15;          // Ph: cid=tid and tid+512
    const int sm2 = (tid + 512) >> 4;                  // (same sh)
    const int sc  = tid >> 3, sh2 = tid & 7;
    const int sc2 = (tid + 512) >> 3;

    uint4 php[4], gp[4];
    auto issue = [&](int s) {
        #pragma unroll
        for (int p = 0; p < 2; ++p) {
            const int m0p = (2 * s + p) * 64;
            php[p*2+0] = *(const uint4*)(pbufT + (bN + m0p + sm ) * CI_ + sh * 8);
            php[p*2+1] = *(const uint4*)(pbufT + (bN + m0p + sm2) * CI_ + sh * 8);
            gp [p*2+0] = *(const uint4*)(gbuf + (bC + sc ) * N_TOK + m0p + sh2 * 8);
            gp [p*2+1] = *(const uint4*)(gbuf + (bC + sc2) * N_TOK + m0p + sh2 * 8);
        }
    };
    issue(0);

    for (int s = 0; s < 32; ++s) {
        __syncthreads();
        // ---- store prefetched tiles (swizzled, same layout as R4) ----
        #pragma unroll
        for (int p = 0; p < 2; ++p) {
            *(uint4*)(smem + PH_OFF(p) + sm  * 256 + ((sh  ^ (sm  & 15)) << 4)) = php[p*2+0];
            *(uint4*)(smem + PH_OFF(p) + sm2 * 256 + ((sh  ^ (sm2 & 15)) << 4)) = php[p*2+1];
            *(uint4*)(smem + G_OFF(p)  + sc  * 160 + ((sh2 ^ (sc  & 7 )) << 4)) = gp[p*2+0];
            *(uint4*)(smem + G_OFF(p)  + sc2 * 160 + ((sh2 ^ (sc2 & 7 )) << 4)) = gp[p*2+1];
        }
        __syncthreads();
        if (s < 31) issue(s + 1);

        // ---- S^T = PhT . theta ----
        f32x4 sacc[4];
        #pragma unroll
        for (int i = 0; i < 4; ++i) sacc[i] = (f32x4){0.f, 0.f, 0.f, 0.f};
        #pragma unroll
        for (int kc = 0; kc < 4; ++kc) {
            #pragma unroll
            for (int msub = 0; msub < 4; ++msub) {
                int m = msub * 16 + col;
                int h = kc * 4 + quad;
                bf16x8 af = *(const bf16x8*)(smem + PH_OFF(ms) + m * 256 + ((h ^ (m & 15)) << 4));
                sacc[msub] = __builtin_amdgcn_mfma_f32_16x16x32_bf16(af, thf[kc], sacc[msub], 0, 0, 0);
            }
        }

        // ---- online softmax (exp2 domain, guarded rescale) ----
        float sl[16];
        #pragma unroll
        for (int i = 0; i < 4; ++i)
            #pragma unroll
            for (int r = 0; r < 4; ++r) sl[i * 4 + r] = sacc[i][r] * LOG2E;
        float tmax = sl[0];
        #pragma unroll
        for (int j = 1; j < 16; ++j) tmax = fmaxf(tmax, sl[j]);
        tmax = fmaxf(tmax, __shfl_xor(tmax, 16));
        tmax = fmaxf(tmax, __shfl_xor(tmax, 32));
        float m_new = fmaxf(m_st, tmax);
        bool chg = m_new > m_st;
        float p16[16], ps = 0.f;
        #pragma unroll
        for (int j = 0; j < 16; ++j) {
            float pv = exp2f(sl[j] - m_new);
            p16[j] = pv;
            ps += pv;
        }
        ps += __shfl_xor(ps, 16);
        ps += __shfl_xor(ps, 32);
        if (__any(chg)) {
            float alpha = exp2f(m_st - m_new);
            l_st = l_st * alpha + ps;
            #pragma unroll
            for (int i = 0; i < 8; ++i) {
                yacc[i][0] *= alpha; yacc[i][1] *= alpha;
                yacc[i][2] *= alpha; yacc[i][3] *= alpha;
            }
        } else {
            l_st += ps;
        }
        m_st = m_new;

        // ---- pack P^T -> per-wave LDS ----
        {
            char* pb = smem + PB_OFF + w * 2048 + col * 128;
            #pragma unroll
            for (int msub = 0; msub < 4; ++msub) {
                #pragma unroll
                for (int pr = 0; pr < 2; ++pr) {
                    u32 d = packbf(p16[msub * 4 + pr * 2], p16[msub * 4 + pr * 2 + 1]);
                    int h = msub * 2 + (quad >> 1);
                    *(u32*)(pb + ((h ^ (col & 7)) << 4) + (quad & 1) * 8 + pr * 4) = d;
                }
            }
        }
        __asm volatile("s_waitcnt lgkmcnt(0)" ::: "memory");

        // ---- PV: y^T[c][q] += G . P^T ----
        bf16x8 pf[2];
        #pragma unroll
        for (int km = 0; km < 2; ++km) {
            int h = km * 4 + quad;
            pf[km] = *(const bf16x8*)(smem + PB_OFF + w * 2048 + col * 128 + ((h ^ (col & 7)) << 4));
        }
        #pragma unroll
        for (int csub = 0; csub < 8; ++csub) {
            #pragma unroll
            for (int km = 0; km < 2; ++km) {
                int c = csub * 16 + col;
                int h = km * 4 + quad;
                bf16x8 gf = *(const bf16x8*)(smem + G_OFF(ms) + c * 160 + ((h ^ (c & 7)) << 4));
                yacc[csub] = __builtin_amdgcn_mfma_f32_16x16x32_bf16(gf, pf[km], yacc[csub], 0, 0, 0);
            }
        }
    }

    // ---- merge m-parity partials ----
    __syncthreads();
    if (ms == 1) {
        char* mb = smem + wq * 8192 + col * 512;
        #pragma unroll
        for (int csub = 0; csub < 8; ++csub)
            *(f32x4*)(mb + (((csub * 4 + quad) ^ col) << 4)) = yacc[csub];
        if (quad == 0) {
            *(float*)(smem + MST_OFF + (wq * 16 + col) * 4) = m_st;
            *(float*)(smem + LST_OFF + (wq * 16 + col) * 4) = l_st;
        }
    }
    __syncthreads();
    if (ms == 0) {
        float m1 = *(const float*)(smem + MST_OFF + (wq * 16 + col) * 4);
        float l1 = *(const float*)(smem + LST_OFF + (wq * 16 + col) * 4);
        float M  = fmaxf(m_st, m1);
        float a0 = exp2f(m_st - M), a1 = exp2f(m1 - M);
        float li = 1.f / (l_st * a0 + l1 * a1);
        float s0 = a0 * li, s1 = a1 * li;
        const char* mb = smem + wq * 8192 + col * 512;
        u16* yo = ytb + (bN + q0 + qw + col) * CI_ + quad * 4;
        #pragma unroll
        for (int csub = 0; csub < 8; ++csub) {
            f32x4 y1 = *(const f32x4*)(mb + (((csub * 4 + quad) ^ col) << 4));
            uint2 pv;
            pv.x = packbf(yacc[csub][0] * s0 + y1[0] * s1, yacc[csub][1] * s0 + y1[1] * s1);
            pv.y = packbf(yacc[csub][2] * s0 + y1[2] * s1, yacc[csub][3] * s0 + y1[3] * s1);
            *(uint2*)(yo + csub * 16) = pv;
        }
    }
}

// =====================================================================
// Kernel C: MFMA outproj + fused BN-stats atomics. 8 waves.
// wave w: o in [32w, 32w+32). n-tile 64. K=128 fully unrolled.
// =====================================================================
__global__ __launch_bounds__(512) void outproj_kernel(
    const u16* __restrict__ wbf, const float* __restrict__ canon,
    const u16* __restrict__ ytb, float* __restrict__ wy, float* __restrict__ stats)
{
    const int b  = blockIdx.y;
    const int n0 = blockIdx.x * 64;
    const int tid = threadIdx.x;
    const int w    = tid >> 6;
    const int lane = tid & 63;
    const int col  = lane & 15;
    const int quad = lane >> 4;
    const int ow   = w * 32;
    const u16* wo = wbf + 98304;
    const size_t bN = (size_t)b * N_TOK;

    f32x4 acc[2][4];
    #pragma unroll
    for (int i = 0; i < 2; ++i)
        #pragma unroll
        for (int j = 0; j < 4; ++j) acc[i][j] = (f32x4){0.f,0.f,0.f,0.f};

    #pragma unroll
    for (int kc = 0; kc < 4; ++kc) {
        bf16x8 bfr[4];
        #pragma unroll
        for (int nf = 0; nf < 4; ++nf)
            bfr[nf] = *(const bf16x8*)&ytb[(bN + n0 + nf * 16 + col) * CI_ + kc * 32 + quad * 8];
        #pragma unroll
        for (int os = 0; os < 2; ++os) {
            bf16x8 afr = *(const bf16x8*)&wo[(size_t)(ow + os * 16 + col) * CI_ + kc * 32 + quad * 8];
            #pragma unroll
            for (int nf = 0; nf < 4; ++nf)
                acc[os][nf] = __builtin_amdgcn_mfma_f32_16x16x32_bf16(afr, bfr[nf], acc[os][nf], 0, 0, 0);
        }
    }

    float s1[2][4], s2[2][4];
    #pragma unroll
    for (int os = 0; os < 2; ++os) {
        int o0 = ow + os * 16 + quad * 4;
        float bb[4];
        #pragma unroll
        for (int i = 0; i < 4; ++i) { bb[i] = canon[131456 + o0 + i]; s1[os][i] = 0.f; s2[os][i] = 0.f; }
        #pragma unroll
        for (int nf = 0; nf < 4; ++nf) {
            #pragma unroll
            for (int i = 0; i < 4; ++i) {
                float v = acc[os][nf][i] + bb[i];
                wy[((size_t)b * C_IN + o0 + i) * N_TOK + n0 + nf * 16 + col] = v;
                s1[os][i] += v;
                s2[os][i] += v * v;
            }
        }
    }
    #pragma unroll
    for (int os = 0; os < 2; ++os)
        #pragma unroll
        for (int i = 0; i < 4; ++i) {
            float a = s1[os][i], q = s2[os][i];
            #pragma unroll
            for (int off = 8; off; off >>= 1) {
                a += __shfl_xor(a, off);
                q += __shfl_xor(q, off);
            }
            s1[os][i] = a; s2[os][i] = q;
        }
    if (col == 0) {
        #pragma unroll
        for (int os = 0; os < 2; ++os)
            #pragma unroll
            for (int i = 0; i < 4; ++i) {
                int o = ow + os * 16 + quad * 4 + i;
                atomicAdd(&stats[o], s1[os][i]);
                atomicAdd(&stats[256 + o], s2[os][i]);
            }
    }
}

// ===================== BN apply + residual (stats finalized inline) =====================
__global__ __launch_bounds__(256) void bnorm_kernel(
    const float* __restrict__ wy, const void* __restrict__ x,
    const float* __restrict__ stats,
    const float* __restrict__ canon, const int* __restrict__ flagp,
    void* __restrict__ outv)
{
    const int flag = *flagp;
    size_t base = ((size_t)blockIdx.x * 256 + threadIdx.x) * 8;
    int o = (int)((base >> 12) & 255);
    float mean = stats[o] * (1.f / 16384.f);
    float var  = stats[256 + o] * (1.f / 16384.f) - mean * mean;
    float r = rsqrtf(var + 1e-5f);
    float gm = canon[131712 + o], bt = canon[131968 + o];
    float4 v0 = *(const float4*)&wy[base];
    float4 v1 = *(const float4*)&wy[base + 4];
    float xf[8]; load8(x, base, flag, xf);
    float ov[8];
    ov[0] = (v0.x - mean) * r * gm + bt + xf[0];
    ov[1] = (v0.y - mean) * r * gm + bt + xf[1];
    ov[2] = (v0.z - mean) * r * gm + bt + xf[2];
    ov[3] = (v0.w - mean) * r * gm + bt + xf[3];
    ov[4] = (v1.x - mean) * r * gm + bt + xf[4];
    ov[5] = (v1.y - mean) * r * gm + bt + xf[5];
    ov[6] = (v1.z - mean) * r * gm + bt + xf[6];
    ov[7] = (v1.w - mean) * r * gm + bt + xf[7];
    if (flag) {
        float* op = (float*)outv + base;
        *(float4*)op       = *(float4*)&ov[0];
        *(float4*)(op + 4) = *(float4*)&ov[4];
    } else {
        uint4 res;
        res.x = packbf(ov[0], ov[1]);
        res.y = packbf(ov[2], ov[3]);
        res.z = packbf(ov[4], ov[5]);
        res.w = packbf(ov[6], ov[7]);
        *(uint4*)((u16*)outv + base) = res;
    }
}

extern "C" void kernel_launch(void* const* d_in, const int* in_sizes, int n_in,
                              void* d_out, int out_size, void* d_ws, size_t ws_size,
                              hipStream_t stream)
{
    const void* x   = d_in[0];
    const void* w_g = d_in[1];
    const void* b_g = d_in[2];
    const void* w_t = d_in[3];
    const void* b_t = d_in[4];
    const void* w_p = d_in[5];
    const void* b_p = d_in[6];
    const void* w_o = d_in[7];
    const void* b_o = d_in[8];
    const void* gm  = d_in[9];
    const void* bt  = d_in[10];

    char* base = (char*)d_ws;
    float* canon    = (float*)base;                    // 132224 f32
    u16*   canon_bf = (u16*)(base + 528896);           // 131072 u16
    int*   flagp    = (int*)(base + 791040);
    float* stats    = (float*)(base + 791296);         // 512 f32
    u16*   gbuf     = (u16*)(base + 1048576);          // 4 MB bf16 [b][c][n]
    u16*   tbufT    = (u16*)(base + 5242880);          // 4 MB bf16 [b][n][c]
    u16*   pbufT    = (u16*)(base + 9437184);          // 4 MB bf16 [b][n][c]
    u16*   ytb      = (u16*)(base + 13631488);         // 4 MB bf16 [b][n][c]
    float* wy       = (float*)(base + 17825792);       // 16 MB f32 [b][o][n]

    detect_kernel<<<1, 64, 0, stream>>>((const u16*)w_g, flagp);
    convert_params_kernel<<<519, 256, 0, stream>>>(w_g, w_t, w_p, w_o, b_g, b_t, b_p, b_o,
                                                   gm, bt, flagp, canon, canon_bf, stats);
    proj_kernel<<<dim3(64, 4), 512, 0, stream>>>(x, canon, canon_bf, flagp, gbuf, tbufT, pbufT);
    attn_kernel<<<dim3(64, 4), 512, 0, stream>>>(tbufT, pbufT, gbuf, ytb);
    outproj_kernel<<<dim3(64, 4), 512, 0, stream>>>(canon_bf, canon, ytb, wy, stats);
    bnorm_kernel<<<2048, 256, 0, stream>>>(wy, x, stats, canon, flagp, d_out);
}

// Round 6
// 188.125 us; speedup vs baseline: 1.4740x; 1.4740x over previous
//
#include <hip/hip_runtime.h>

#define N_TOK 4096
#define C_IN 256
#define CI_ 128

typedef unsigned short u16;
typedef unsigned int   u32;
typedef __attribute__((ext_vector_type(8))) short bf16x8;
typedef __attribute__((ext_vector_type(4))) float f32x4;

// ---- bf16 helpers ----
__device__ __forceinline__ float lo16f(u32 u){ union{u32 i; float f;} c; c.i = u << 16; return c.f; }
__device__ __forceinline__ float hi16f(u32 u){ union{u32 i; float f;} c; c.i = u & 0xffff0000u; return c.f; }
__device__ __forceinline__ void bf8f(const uint4 u, float* f){
    f[0]=lo16f(u.x); f[1]=hi16f(u.x); f[2]=lo16f(u.y); f[3]=hi16f(u.y);
    f[4]=lo16f(u.z); f[5]=hi16f(u.z); f[6]=lo16f(u.w); f[7]=hi16f(u.w);
}
__device__ __forceinline__ float bf1f(u16 v){ union{u32 i; float f;} c; c.i = ((u32)v)<<16; return c.f; }
__device__ __forceinline__ u16 f2bf(float f){
    union{float f; u32 i;} c; c.f = f;
    u32 i = c.i;
    u32 r = (i + 0x7fffu + ((i >> 16) & 1u)) >> 16;   // RNE
    return (u16)r;
}
__device__ __forceinline__ u32 packbf(float a, float b){
    return (u32)f2bf(a) | ((u32)f2bf(b) << 16);
}

__device__ __forceinline__ void load8(const void* base, size_t idx, int flag, float* f){
    if (flag) {
        const float* p = (const float*)base + idx;
        *(float4*)&f[0] = *(const float4*)p;
        *(float4*)&f[4] = *(const float4*)(p + 4);
    } else {
        uint4 u = *(const uint4*)((const u16*)base + idx);
        bf8f(u, f);
    }
}
__device__ __forceinline__ void load4(const void* base, size_t idx, int flag, float* f){
    if (flag) {
        float4 v = *(const float4*)((const float*)base + idx);
        f[0]=v.x; f[1]=v.y; f[2]=v.z; f[3]=v.w;
    } else {
        uint2 u = *(const uint2*)((const u16*)base + idx);
        f[0]=lo16f(u.x); f[1]=hi16f(u.x); f[2]=lo16f(u.y); f[3]=hi16f(u.y);
    }
}

// ===================== param canonicalize (+flag inline, +stats zero) =====================
__global__ __launch_bounds__(256) void convert_params_kernel(
    const void* wg, const void* wt, const void* wp, const void* wo,
    const void* bg, const void* bt, const void* bp, const void* bo,
    const void* gm, const void* bt2,
    int* __restrict__ flagp, float* __restrict__ canon, u16* __restrict__ canon_bf,
    float* __restrict__ stats)
{
    __shared__ int sflag;
    const int tid = threadIdx.x;
    if (tid < 64) {   // wave 0: detect dtype from wg (std=0.01 weights)
        int cnt = 0;
        const u16* wgp = (const u16*)wg;
        for (int i = tid; i < 256; i += 64) {
            u16 v = wgp[2 * i];
            if (((v >> 7) & 0xFF) >= 128) cnt++;
        }
        #pragma unroll
        for (int off = 32; off; off >>= 1) cnt += __shfl_down(cnt, off);
        if (tid == 0) sflag = (cnt >= 8) ? 1 : 0;
    }
    __syncthreads();
    const int f = sflag;
    if (blockIdx.x == 0 && tid == 0) *flagp = f;

    int idx = blockIdx.x * 256 + tid;
    if (idx >= 132224) {
        int j = idx - 132224;
        if (j < 4096) stats[j] = 0.f;
        return;
    }
    const void* src; int loc;
    if      (idx < 32768)  { src = wg;  loc = idx; }
    else if (idx < 65536)  { src = wt;  loc = idx - 32768; }
    else if (idx < 98304)  { src = wp;  loc = idx - 65536; }
    else if (idx < 131072) { src = wo;  loc = idx - 98304; }
    else if (idx < 131200) { src = bg;  loc = idx - 131072; }
    else if (idx < 131328) { src = bt;  loc = idx - 131200; }
    else if (idx < 131456) { src = bp;  loc = idx - 131328; }
    else if (idx < 131712) { src = bo;  loc = idx - 131456; }
    else if (idx < 131968) { src = gm;  loc = idx - 131712; }
    else                   { src = bt2; loc = idx - 131968; }
    float v = f ? ((const float*)src)[loc] : bf1f(((const u16*)src)[loc]);
    canon[idx] = v;
    if (idx < 131072) canon_bf[idx] = f2bf(v);
}

// =====================================================================
// Kernel A: MFMA projections, 8 waves, one-ahead x prefetch (R5 version).
// =====================================================================
__global__ __launch_bounds__(512) void proj_kernel(
    const void* __restrict__ x, const float* __restrict__ canon,
    const u16* __restrict__ wbf, const int* __restrict__ flagp,
    u16* __restrict__ gbuf, u16* __restrict__ tbufT, u16* __restrict__ pbufT)
{
    __shared__ __align__(16) u16 plds[64 * 400];
    const int flag = *flagp;
    const int b  = blockIdx.y;
    const int n0 = blockIdx.x * 64;
    const int tid = threadIdx.x;
    const int w    = tid >> 6;
    const int lane = tid & 63;
    const int col  = lane & 15;
    const int quad = lane >> 4;
    const int rw   = w * 48;

    f32x4 acc[3][4];
    #pragma unroll
    for (int i = 0; i < 3; ++i)
        #pragma unroll
        for (int j = 0; j < 4; ++j) acc[i][j] = (f32x4){0.f,0.f,0.f,0.f};

    const size_t xb = (size_t)b * C_IN * N_TOK;
    const int sk  = tid >> 4;
    const int sn4 = (tid & 15) * 4;
    const int skk = sk ^ (((sn4 >> 3) & 3) << 3);

    float pre[4];
    load4(x, xb + (size_t)sk * N_TOK + n0 + sn4, flag, pre);

    for (int kc = 0; kc < 8; ++kc) {
        const int k0 = kc * 32;
        __syncthreads();
        #pragma unroll
        for (int i = 0; i < 4; ++i) plds[(sn4 + i) * 40 + skk] = f2bf(pre[i]);
        __syncthreads();
        if (kc < 7)
            load4(x, xb + (size_t)(k0 + 32 + sk) * N_TOK + n0 + sn4, flag, pre);
        bf16x8 bfr[4];
        #pragma unroll
        for (int nf = 0; nf < 4; ++nf) {
            int n = nf * 16 + col;
            int q2 = quad ^ ((n >> 3) & 3);
            bfr[nf] = *(const bf16x8*)&plds[n * 40 + q2 * 8];
        }
        #pragma unroll
        for (int rs = 0; rs < 3; ++rs) {
            bf16x8 afr = *(const bf16x8*)&wbf[(size_t)(rw + rs * 16 + col) * 256 + k0 + quad * 8];
            #pragma unroll
            for (int nf = 0; nf < 4; ++nf)
                acc[rs][nf] = __builtin_amdgcn_mfma_f32_16x16x32_bf16(afr, bfr[nf], acc[rs][nf], 0, 0, 0);
        }
    }

    __syncthreads();
    #pragma unroll
    for (int rs = 0; rs < 3; ++rs) {
        int r0 = rw + rs * 16 + quad * 4;
        float b0 = canon[131072 + r0 + 0];
        float b1 = canon[131072 + r0 + 1];
        float b2 = canon[131072 + r0 + 2];
        float b3 = canon[131072 + r0 + 3];
        #pragma unroll
        for (int nf = 0; nf < 4; ++nf) {
            int n = nf * 16 + col;
            uint2 pv;
            pv.x = packbf(acc[rs][nf][0] + b0, acc[rs][nf][1] + b1);
            pv.y = packbf(acc[rs][nf][2] + b2, acc[rs][nf][3] + b3);
            *(uint2*)&plds[n * 400 + r0] = pv;
        }
    }
    __syncthreads();

    const size_t bN = (size_t)b * N_TOK;
    {
        int r = tid & 127, nq = tid >> 7;
        u16 tmp[16];
        #pragma unroll
        for (int j = 0; j < 16; ++j) tmp[j] = plds[(nq * 16 + j) * 400 + r];
        u16* dst = &gbuf[((size_t)b * CI_ + r) * N_TOK + n0 + nq * 16];
        *(uint4*)(dst + 0) = *(uint4*)&tmp[0];
        *(uint4*)(dst + 8) = *(uint4*)&tmp[8];
    }
    {
        int n = tid & 63, part = tid >> 6;
        const u16* src = (part < 4) ? &plds[n * 400 + 128 + part * 32]
                                    : &plds[n * 400 + 256 + (part - 4) * 32];
        u16* dst = (part < 4) ? &tbufT[(bN + n0 + n) * CI_ + part * 32]
                              : &pbufT[(bN + n0 + n) * CI_ + (part - 4) * 32];
        #pragma unroll
        for (int v = 0; v < 4; ++v) *(uint4*)(dst + v * 8) = *(const uint4*)(src + v * 8);
    }
}

// =====================================================================
// Kernel B: MFMA flash attention (R4-verbatim main loop) + fused outproj
// + bucketed BN-stats epilogue. wy written bf16 [b][o][n].
// =====================================================================
#define PH_OFF(p) ((p) * 16384)
#define G_OFF(p)  (32768 + (p) * 20480)
#define PB_OFF    73728
#define MST_OFF   90112
#define LST_OFF   90368
#define SMEM_SZ   90624
#define YB_OFF    32768   // epilogue: [64 q][128 c] bf16, 256B rows, chunk-swizzled

__global__ __launch_bounds__(512) void attn_kernel(
    const u16* __restrict__ tbufT, const u16* __restrict__ pbufT,
    const u16* __restrict__ gbuf,
    const u16* __restrict__ wbf, const float* __restrict__ canon,
    u16* __restrict__ wyb, float* __restrict__ stats)
{
    __shared__ __align__(16) char smem[SMEM_SZ];
    const int b   = blockIdx.y;
    const int q0  = blockIdx.x * 64;
    const int tid = threadIdx.x;
    const int w    = tid >> 6;
    const int lane = tid & 63;
    const int col  = lane & 15;
    const int quad = lane >> 4;
    const int wq   = w & 3;
    const int ms   = w >> 2;
    const int qw   = wq * 16;

    bf16x8 thf[4];
    {
        const u16* tb = tbufT + ((size_t)b * N_TOK + q0 + qw + col) * CI_;
        #pragma unroll
        for (int kc = 0; kc < 4; ++kc)
            thf[kc] = *(const bf16x8*)(tb + kc * 32 + quad * 8);
    }

    f32x4 yacc[8];
    #pragma unroll
    for (int i = 0; i < 8; ++i) yacc[i] = (f32x4){0.f, 0.f, 0.f, 0.f};
    float m_st = -3.0e38f, l_st = 0.f;

    const size_t bN = (size_t)b * N_TOK;
    const size_t bC = (size_t)b * CI_;

    for (int s = 0; s < 32; ++s) {
        __syncthreads();
        #pragma unroll
        for (int p = 0; p < 2; ++p) {
            const int m0p = (2 * s + p) * 64;
            #pragma unroll
            for (int i = 0; i < 2; ++i) {
                int cid = i * 512 + tid;
                int m = cid >> 4, h = cid & 15;
                uint4 v = *(const uint4*)(pbufT + (bN + m0p + m) * CI_ + h * 8);
                *(uint4*)(smem + PH_OFF(p) + m * 256 + ((h ^ (m & 15)) << 4)) = v;
            }
            #pragma unroll
            for (int i = 0; i < 2; ++i) {
                int cid = i * 512 + tid;
                int c = cid >> 3, h = cid & 7;
                uint4 v = *(const uint4*)(gbuf + (bC + c) * N_TOK + m0p + h * 8);
                *(uint4*)(smem + G_OFF(p) + c * 160 + ((h ^ (c & 7)) << 4)) = v;
            }
        }
        __syncthreads();

        f32x4 sacc[4];
        #pragma unroll
        for (int i = 0; i < 4; ++i) sacc[i] = (f32x4){0.f, 0.f, 0.f, 0.f};
        #pragma unroll
        for (int kc = 0; kc < 4; ++kc) {
            #pragma unroll
            for (int msub = 0; msub < 4; ++msub) {
                int m = msub * 16 + col;
                int h = kc * 4 + quad;
                bf16x8 af = *(const bf16x8*)(smem + PH_OFF(ms) + m * 256 + ((h ^ (m & 15)) << 4));
                sacc[msub] = __builtin_amdgcn_mfma_f32_16x16x32_bf16(af, thf[kc], sacc[msub], 0, 0, 0);
            }
        }

        float tmax = sacc[0][0];
        #pragma unroll
        for (int i = 0; i < 4; ++i)
            #pragma unroll
            for (int r = 0; r < 4; ++r) tmax = fmaxf(tmax, sacc[i][r]);
        tmax = fmaxf(tmax, __shfl_xor(tmax, 16));
        tmax = fmaxf(tmax, __shfl_xor(tmax, 32));
        float m_new = fmaxf(m_st, tmax);
        float p16[16], ps = 0.f;
        #pragma unroll
        for (int i = 0; i < 4; ++i)
            #pragma unroll
            for (int r = 0; r < 4; ++r) {
                float pv = __expf(sacc[i][r] - m_new);
                p16[i * 4 + r] = pv;
                ps += pv;
            }
        ps += __shfl_xor(ps, 16);
        ps += __shfl_xor(ps, 32);
        float alpha = __expf(m_st - m_new);
        l_st = l_st * alpha + ps;
        m_st = m_new;
        #pragma unroll
        for (int i = 0; i < 8; ++i) {
            yacc[i][0] *= alpha; yacc[i][1] *= alpha;
            yacc[i][2] *= alpha; yacc[i][3] *= alpha;
        }

        {
            char* pb = smem + PB_OFF + w * 2048 + col * 128;
            #pragma unroll
            for (int msub = 0; msub < 4; ++msub) {
                #pragma unroll
                for (int pr = 0; pr < 2; ++pr) {
                    u32 d = packbf(p16[msub * 4 + pr * 2], p16[msub * 4 + pr * 2 + 1]);
                    int h = msub * 2 + (quad >> 1);
                    *(u32*)(pb + ((h ^ (col & 7)) << 4) + (quad & 1) * 8 + pr * 4) = d;
                }
            }
        }
        __asm volatile("s_waitcnt lgkmcnt(0)" ::: "memory");

        bf16x8 pf[2];
        #pragma unroll
        for (int km = 0; km < 2; ++km) {
            int h = km * 4 + quad;
            pf[km] = *(const bf16x8*)(smem + PB_OFF + w * 2048 + col * 128 + ((h ^ (col & 7)) << 4));
        }
        #pragma unroll
        for (int csub = 0; csub < 8; ++csub) {
            #pragma unroll
            for (int km = 0; km < 2; ++km) {
                int c = csub * 16 + col;
                int h = km * 4 + quad;
                bf16x8 gf = *(const bf16x8*)(smem + G_OFF(ms) + c * 160 + ((h ^ (c & 7)) << 4));
                yacc[csub] = __builtin_amdgcn_mfma_f32_16x16x32_bf16(gf, pf[km], yacc[csub], 0, 0, 0);
            }
        }
    }

    // ---- merge m-parity partials; merged y -> LDS yB (B-operand layout) ----
    __syncthreads();
    if (ms == 1) {
        char* mb = smem + wq * 8192 + col * 512;
        #pragma unroll
        for (int csub = 0; csub < 8; ++csub)
            *(f32x4*)(mb + (((csub * 4 + quad) ^ col) << 4)) = yacc[csub];
        if (quad == 0) {
            *(float*)(smem + MST_OFF + (wq * 16 + col) * 4) = m_st;
            *(float*)(smem + LST_OFF + (wq * 16 + col) * 4) = l_st;
        }
    }
    __syncthreads();
    if (ms == 0) {
        float m1 = *(const float*)(smem + MST_OFF + (wq * 16 + col) * 4);
        float l1 = *(const float*)(smem + LST_OFF + (wq * 16 + col) * 4);
        float M  = fmaxf(m_st, m1);
        float a0 = __expf(m_st - M), a1 = __expf(m1 - M);
        float li = 1.f / (l_st * a0 + l1 * a1);
        float s0 = a0 * li, s1 = a1 * li;
        const char* mb = smem + wq * 8192 + col * 512;
        const int q = qw + col;
        #pragma unroll
        for (int csub = 0; csub < 8; ++csub) {
            f32x4 y1 = *(const f32x4*)(mb + (((csub * 4 + quad) ^ col) << 4));
            uint2 pv;
            pv.x = packbf(yacc[csub][0] * s0 + y1[0] * s1, yacc[csub][1] * s0 + y1[1] * s1);
            pv.y = packbf(yacc[csub][2] * s0 + y1[2] * s1, yacc[csub][3] * s0 + y1[3] * s1);
            int chunk = csub * 2 + (quad >> 1);
            *(uint2*)(smem + YB_OFF + q * 256 + ((chunk ^ (q & 15)) << 4) + (quad & 1) * 8) = pv;
        }
    }
    __syncthreads();

    // ---- fused outproj: W_y[o][q] = sum_c wo[o][c] * y[c][q] + bo ----
    const u16* wo = wbf + 98304;
    f32x4 oacc[2][4];
    #pragma unroll
    for (int i = 0; i < 2; ++i)
        #pragma unroll
        for (int j = 0; j < 4; ++j) oacc[i][j] = (f32x4){0.f,0.f,0.f,0.f};
    #pragma unroll
    for (int kc = 0; kc < 4; ++kc) {
        bf16x8 bqf[4];
        #pragma unroll
        for (int qf = 0; qf < 4; ++qf) {
            int q = qf * 16 + col;
            int h = kc * 4 + quad;
            bqf[qf] = *(const bf16x8*)(smem + YB_OFF + q * 256 + ((h ^ (q & 15)) << 4));
        }
        #pragma unroll
        for (int os = 0; os < 2; ++os) {
            bf16x8 afr = *(const bf16x8*)&wo[(size_t)(w * 32 + os * 16 + col) * CI_ + kc * 32 + quad * 8];
            #pragma unroll
            for (int qf = 0; qf < 4; ++qf)
                oacc[os][qf] = __builtin_amdgcn_mfma_f32_16x16x32_bf16(afr, bqf[qf], oacc[os][qf], 0, 0, 0);
        }
    }
    // bias + bf16 store + bucketed stats
    const int bucket = (blockIdx.x + blockIdx.y) & 7;
    float* sb = stats + bucket * 512;
    #pragma unroll
    for (int os = 0; os < 2; ++os) {
        int ob = w * 32 + os * 16 + quad * 4;
        #pragma unroll
        for (int i = 0; i < 4; ++i) {
            float bb = canon[131456 + ob + i];
            float s1 = 0.f, s2 = 0.f;
            u16* dst = &wyb[((size_t)b * C_IN + ob + i) * N_TOK + q0 + col];
            #pragma unroll
            for (int qf = 0; qf < 4; ++qf) {
                float v = oacc[os][qf][i] + bb;
                dst[qf * 16] = f2bf(v);
                s1 += v;
                s2 += v * v;
            }
            #pragma unroll
            for (int off = 8; off; off >>= 1) {
                s1 += __shfl_xor(s1, off);
                s2 += __shfl_xor(s2, off);
            }
            if (col == 0) {
                atomicAdd(&sb[ob + i], s1);
                atomicAdd(&sb[256 + ob + i], s2);
            }
        }
    }
}

// ===================== BN apply + residual (stats finalized inline) =====================
__global__ __launch_bounds__(256) void bnorm_kernel(
    const u16* __restrict__ wyb, const void* __restrict__ x,
    const float* __restrict__ stats,
    const float* __restrict__ canon, const int* __restrict__ flagp,
    void* __restrict__ outv)
{
    const int flag = *flagp;
    size_t base = ((size_t)blockIdx.x * 256 + threadIdx.x) * 8;
    int o = (int)((base >> 12) & 255);
    float sum1 = 0.f, sum2 = 0.f;
    #pragma unroll
    for (int k = 0; k < 8; ++k) {
        sum1 += stats[k * 512 + o];
        sum2 += stats[k * 512 + 256 + o];
    }
    float mean = sum1 * (1.f / 16384.f);
    float var  = sum2 * (1.f / 16384.f) - mean * mean;
    float r = rsqrtf(var + 1e-5f);
    float gm = canon[131712 + o], bt = canon[131968 + o];
    uint4 wu = *(const uint4*)&wyb[base];
    float wv[8]; bf8f(wu, wv);
    float xf[8]; load8(x, base, flag, xf);
    float ov[8];
    #pragma unroll
    for (int i = 0; i < 8; ++i)
        ov[i] = (wv[i] - mean) * r * gm + bt + xf[i];
    if (flag) {
        float* op = (float*)outv + base;
        *(float4*)op       = *(float4*)&ov[0];
        *(float4*)(op + 4) = *(float4*)&ov[4];
    } else {
        uint4 res;
        res.x = packbf(ov[0], ov[1]);
        res.y = packbf(ov[2], ov[3]);
        res.z = packbf(ov[4], ov[5]);
        res.w = packbf(ov[6], ov[7]);
        *(uint4*)((u16*)outv + base) = res;
    }
}

extern "C" void kernel_launch(void* const* d_in, const int* in_sizes, int n_in,
                              void* d_out, int out_size, void* d_ws, size_t ws_size,
                              hipStream_t stream)
{
    const void* x   = d_in[0];
    const void* w_g = d_in[1];
    const void* b_g = d_in[2];
    const void* w_t = d_in[3];
    const void* b_t = d_in[4];
    const void* w_p = d_in[5];
    const void* b_p = d_in[6];
    const void* w_o = d_in[7];
    const void* b_o = d_in[8];
    const void* gm  = d_in[9];
    const void* bt  = d_in[10];

    char* base = (char*)d_ws;
    float* canon    = (float*)base;                    // 132224 f32
    u16*   canon_bf = (u16*)(base + 528896);           // 131072 u16
    int*   flagp    = (int*)(base + 791040);
    float* stats    = (float*)(base + 791296);         // 8 buckets x 512 f32 = 16 KB
    u16*   gbuf     = (u16*)(base + 1048576);          // 4 MB bf16 [b][c][n]
    u16*   tbufT    = (u16*)(base + 5242880);          // 4 MB bf16 [b][n][c]
    u16*   pbufT    = (u16*)(base + 9437184);          // 4 MB bf16 [b][n][c]
    u16*   wyb      = (u16*)(base + 13631488);         // 8 MB bf16 [b][o][n]

    convert_params_kernel<<<533, 256, 0, stream>>>(w_g, w_t, w_p, w_o, b_g, b_t, b_p, b_o,
                                                   gm, bt, flagp, canon, canon_bf, stats);
    proj_kernel<<<dim3(64, 4), 512, 0, stream>>>(x, canon, canon_bf, flagp, gbuf, tbufT, pbufT);
    attn_kernel<<<dim3(64, 4), 512, 0, stream>>>(tbufT, pbufT, gbuf, canon_bf, canon, wyb, stats);
    bnorm_kernel<<<2048, 256, 0, stream>>>(wyb, x, stats, canon, flagp, d_out);
}

// Round 7
// 188.002 us; speedup vs baseline: 1.4750x; 1.0007x over previous
//
#include <hip/hip_runtime.h>

#define N_TOK 4096
#define C_IN 256
#define CI_ 128

typedef unsigned short u16;
typedef unsigned int   u32;
typedef __attribute__((ext_vector_type(8))) short bf16x8;
typedef __attribute__((ext_vector_type(4))) float f32x4;

// ---- bf16 helpers ----
__device__ __forceinline__ float lo16f(u32 u){ union{u32 i; float f;} c; c.i = u << 16; return c.f; }
__device__ __forceinline__ float hi16f(u32 u){ union{u32 i; float f;} c; c.i = u & 0xffff0000u; return c.f; }
__device__ __forceinline__ void bf8f(const uint4 u, float* f){
    f[0]=lo16f(u.x); f[1]=hi16f(u.x); f[2]=lo16f(u.y); f[3]=hi16f(u.y);
    f[4]=lo16f(u.z); f[5]=hi16f(u.z); f[6]=lo16f(u.w); f[7]=hi16f(u.w);
}
__device__ __forceinline__ float bf1f(u16 v){ union{u32 i; float f;} c; c.i = ((u32)v)<<16; return c.f; }
__device__ __forceinline__ u16 f2bf(float f){
    union{float f; u32 i;} c; c.f = f;
    u32 i = c.i;
    u32 r = (i + 0x7fffu + ((i >> 16) & 1u)) >> 16;   // RNE
    return (u16)r;
}
__device__ __forceinline__ u32 packbf(float a, float b){
    return (u32)f2bf(a) | ((u32)f2bf(b) << 16);
}

__device__ __forceinline__ void load8(const void* base, size_t idx, int flag, float* f){
    if (flag) {
        const float* p = (const float*)base + idx;
        *(float4*)&f[0] = *(const float4*)p;
        *(float4*)&f[4] = *(const float4*)(p + 4);
    } else {
        uint4 u = *(const uint4*)((const u16*)base + idx);
        bf8f(u, f);
    }
}
__device__ __forceinline__ void load4(const void* base, size_t idx, int flag, float* f){
    if (flag) {
        float4 v = *(const float4*)((const float*)base + idx);
        f[0]=v.x; f[1]=v.y; f[2]=v.z; f[3]=v.w;
    } else {
        uint2 u = *(const uint2*)((const u16*)base + idx);
        f[0]=lo16f(u.x); f[1]=hi16f(u.x); f[2]=lo16f(u.y); f[3]=hi16f(u.y);
    }
}

// async global->LDS DMA, 16B per lane, dest = wave-uniform base + lane*16
__device__ __forceinline__ void dma16(const u16* g, char* l){
    __builtin_amdgcn_global_load_lds(
        (const __attribute__((address_space(1))) u32*)g,
        (__attribute__((address_space(3))) u32*)l, 16, 0, 0);
}

// ===================== param canonicalize (+flag inline, +stats zero) =====================
__global__ __launch_bounds__(256) void convert_params_kernel(
    const void* wg, const void* wt, const void* wp, const void* wo,
    const void* bg, const void* bt, const void* bp, const void* bo,
    const void* gm, const void* bt2,
    int* __restrict__ flagp, float* __restrict__ canon, u16* __restrict__ canon_bf,
    float* __restrict__ stats)
{
    __shared__ int sflag;
    const int tid = threadIdx.x;
    if (tid < 64) {
        int cnt = 0;
        const u16* wgp = (const u16*)wg;
        for (int i = tid; i < 256; i += 64) {
            u16 v = wgp[2 * i];
            if (((v >> 7) & 0xFF) >= 128) cnt++;
        }
        #pragma unroll
        for (int off = 32; off; off >>= 1) cnt += __shfl_down(cnt, off);
        if (tid == 0) sflag = (cnt >= 8) ? 1 : 0;
    }
    __syncthreads();
    const int f = sflag;
    if (blockIdx.x == 0 && tid == 0) *flagp = f;

    int idx = blockIdx.x * 256 + tid;
    if (idx >= 132224) {
        int j = idx - 132224;
        if (j < 4096) stats[j] = 0.f;
        return;
    }
    const void* src; int loc;
    if      (idx < 32768)  { src = wg;  loc = idx; }
    else if (idx < 65536)  { src = wt;  loc = idx - 32768; }
    else if (idx < 98304)  { src = wp;  loc = idx - 65536; }
    else if (idx < 131072) { src = wo;  loc = idx - 98304; }
    else if (idx < 131200) { src = bg;  loc = idx - 131072; }
    else if (idx < 131328) { src = bt;  loc = idx - 131200; }
    else if (idx < 131456) { src = bp;  loc = idx - 131328; }
    else if (idx < 131712) { src = bo;  loc = idx - 131456; }
    else if (idx < 131968) { src = gm;  loc = idx - 131712; }
    else                   { src = bt2; loc = idx - 131968; }
    float v = f ? ((const float*)src)[loc] : bf1f(((const u16*)src)[loc]);
    canon[idx] = v;
    if (idx < 131072) canon_bf[idx] = f2bf(v);
}

// =====================================================================
// Kernel X: x [b][k][n] (fp32 or bf16) -> xbfT [b][n][k] bf16
// =====================================================================
__global__ __launch_bounds__(256) void xpose_kernel(
    const void* __restrict__ x, const int* __restrict__ flagp, u16* __restrict__ xbfT)
{
    __shared__ u16 t[64][72];
    const int flag = *flagp;
    const int b = blockIdx.z, k0 = blockIdx.y * 64, n0 = blockIdx.x * 64;
    const int tid = threadIdx.x;
    const size_t xb = (size_t)b * C_IN * N_TOK;
    {
        int kk = tid >> 4, n4 = (tid & 15) * 4;
        #pragma unroll
        for (int i = 0; i < 4; ++i) {
            float f[4];
            load4(x, xb + (size_t)(k0 + kk + i * 16) * N_TOK + n0 + n4, flag, f);
            #pragma unroll
            for (int j = 0; j < 4; ++j) t[n4 + j][kk + i * 16] = f2bf(f[j]);
        }
    }
    __syncthreads();
    {
        int kq = tid & 3, n = tid >> 2;
        u16* dst = &xbfT[((size_t)b * N_TOK + n0 + n) * C_IN + k0 + kq * 16];
        *(uint4*)(dst + 0) = *(const uint4*)&t[n][kq * 16];
        *(uint4*)(dst + 8) = *(const uint4*)&t[n][kq * 16 + 8];
    }
}

// =====================================================================
// Kernel A: MFMA projections, barrier-free K-loop (direct frag loads).
// wave w: r in [48w, 48w+48). n-tile 64.
// =====================================================================
__global__ __launch_bounds__(512) void proj_kernel(
    const u16* __restrict__ xbfT, const float* __restrict__ canon,
    const u16* __restrict__ wbf,
    u16* __restrict__ gbuf, u16* __restrict__ tbufT, u16* __restrict__ pbufT)
{
    __shared__ __align__(16) u16 plds[64 * 400];
    const int b  = blockIdx.y;
    const int n0 = blockIdx.x * 64;
    const int tid = threadIdx.x;
    const int w    = tid >> 6;
    const int lane = tid & 63;
    const int col  = lane & 15;
    const int quad = lane >> 4;
    const int rw   = w * 48;
    const size_t bN = (size_t)b * N_TOK;

    f32x4 acc[3][4];
    #pragma unroll
    for (int i = 0; i < 3; ++i)
        #pragma unroll
        for (int j = 0; j < 4; ++j) acc[i][j] = (f32x4){0.f,0.f,0.f,0.f};

    #pragma unroll
    for (int kc = 0; kc < 8; ++kc) {
        bf16x8 bfr[4];
        #pragma unroll
        for (int nf = 0; nf < 4; ++nf)
            bfr[nf] = *(const bf16x8*)&xbfT[(bN + n0 + nf * 16 + col) * C_IN + kc * 32 + quad * 8];
        #pragma unroll
        for (int rs = 0; rs < 3; ++rs) {
            bf16x8 afr = *(const bf16x8*)&wbf[(size_t)(rw + rs * 16 + col) * 256 + kc * 32 + quad * 8];
            #pragma unroll
            for (int nf = 0; nf < 4; ++nf)
                acc[rs][nf] = __builtin_amdgcn_mfma_f32_16x16x32_bf16(afr, bfr[nf], acc[rs][nf], 0, 0, 0);
        }
    }

    // ---- bias + restage C to LDS cl[n][r] ----
    #pragma unroll
    for (int rs = 0; rs < 3; ++rs) {
        int r0 = rw + rs * 16 + quad * 4;
        float b0 = canon[131072 + r0 + 0];
        float b1 = canon[131072 + r0 + 1];
        float b2 = canon[131072 + r0 + 2];
        float b3 = canon[131072 + r0 + 3];
        #pragma unroll
        for (int nf = 0; nf < 4; ++nf) {
            int n = nf * 16 + col;
            uint2 pv;
            pv.x = packbf(acc[rs][nf][0] + b0, acc[rs][nf][1] + b1);
            pv.y = packbf(acc[rs][nf][2] + b2, acc[rs][nf][3] + b3);
            *(uint2*)&plds[n * 400 + r0] = pv;
        }
    }
    __syncthreads();

    {
        int r = tid & 127, nq = tid >> 7;
        u16 tmp[16];
        #pragma unroll
        for (int j = 0; j < 16; ++j) tmp[j] = plds[(nq * 16 + j) * 400 + r];
        u16* dst = &gbuf[((size_t)b * CI_ + r) * N_TOK + n0 + nq * 16];
        *(uint4*)(dst + 0) = *(uint4*)&tmp[0];
        *(uint4*)(dst + 8) = *(uint4*)&tmp[8];
    }
    {
        int n = tid & 63, part = tid >> 6;
        const u16* src = (part < 4) ? &plds[n * 400 + 128 + part * 32]
                                    : &plds[n * 400 + 256 + (part - 4) * 32];
        u16* dst = (part < 4) ? &tbufT[(bN + n0 + n) * CI_ + part * 32]
                              : &pbufT[(bN + n0 + n) * CI_ + (part - 4) * 32];
        #pragma unroll
        for (int v = 0; v < 4; ++v) *(uint4*)(dst + v * 8) = *(const uint4*)(src + v * 8);
    }
}

// =====================================================================
// Kernel B: MFMA flash attention, async double-buffered DMA staging,
// fused outproj + bucketed BN-stats epilogue.
// LDS: Ph 2buf x 2par x 16KB @0; G 2buf x 2par x 16KB @65536;
//      PB 8x2KB @131072; MST/LST @147456/147712. Merge/yB reuse @0/@32768.
// =====================================================================
#define PB2   131072
#define MST2  147456
#define LST2  147712
#define SMEM2 147968

__global__ __launch_bounds__(512) void attn_kernel(
    const u16* __restrict__ tbufT, const u16* __restrict__ pbufT,
    const u16* __restrict__ gbuf,
    const u16* __restrict__ wbf, const float* __restrict__ canon,
    u16* __restrict__ wyb, float* __restrict__ stats)
{
    __shared__ __align__(16) char smem[SMEM2];
    const int b   = blockIdx.y;
    const int q0  = blockIdx.x * 64;
    const int tid = threadIdx.x;
    const int w    = tid >> 6;
    const int lane = tid & 63;
    const int col  = lane & 15;
    const int quad = lane >> 4;
    const int wq   = w & 3;
    const int ms   = w >> 2;
    const int qw   = wq * 16;
    const size_t bN = (size_t)b * N_TOK;
    const size_t bC = (size_t)b * CI_;

    bf16x8 thf[4];
    {
        const u16* tb = tbufT + (bN + q0 + qw + col) * CI_;
        #pragma unroll
        for (int kc = 0; kc < 4; ++kc)
            thf[kc] = *(const bf16x8*)(tb + kc * 32 + quad * 8);
    }

    // ---- DMA descriptors: waves 0-3 stage Ph, waves 4-7 stage G ----
    const u16* sb[8];
    int ldso[8];
    int sstep;
    if (w < 4) {
        int r = lane >> 4, cp = lane & 15;
        sstep = 128 * CI_;
        #pragma unroll
        for (int j = 0; j < 8; ++j) {
            int seg = w * 8 + j, p = seg >> 4, m0 = (seg & 15) * 4;
            int m = m0 + r, h = cp ^ (m & 15);
            sb[j] = pbufT + (bN + p * 64 + m) * CI_ + h * 8;
            ldso[j] = p * 16384 + m0 * 256;
        }
    } else {
        int r = lane >> 3, cp = lane & 7;
        sstep = 128;
        #pragma unroll
        for (int j = 0; j < 8; ++j) {
            int seg = (w - 4) * 8 + j, p = seg >> 4, c0 = (seg & 15) * 8;
            int c = c0 + r, h = cp ^ (c & 7);
            sb[j] = gbuf + (bC + c) * N_TOK + p * 64 + h * 8;
            ldso[j] = 65536 + p * 16384 + c0 * 128;
        }
    }

    f32x4 yacc[8];
    #pragma unroll
    for (int i = 0; i < 8; ++i) yacc[i] = (f32x4){0.f, 0.f, 0.f, 0.f};
    float m_st = -3.0e38f, l_st = 0.f;

    // prologue: issue tile 0 into buf 0
    #pragma unroll
    for (int j = 0; j < 8; ++j) dma16(sb[j], smem + ldso[j]);

    for (int s = 0; s < 32; ++s) {
        const int bb = (s & 1) << 15;
        __asm volatile("s_waitcnt lgkmcnt(0)" ::: "memory");
        __asm volatile("s_barrier" ::: "memory");          // all done reading buf^1
        if (s < 31) {
            const int nb = ((s + 1) & 1) << 15;
            const size_t so = (size_t)(s + 1) * sstep;
            #pragma unroll
            for (int j = 0; j < 8; ++j) dma16(sb[j] + so, smem + nb + ldso[j]);
            __asm volatile("s_waitcnt vmcnt(8)" ::: "memory");   // tile-s DMAs retired
        } else {
            __asm volatile("s_waitcnt vmcnt(0)" ::: "memory");
        }
        __asm volatile("s_barrier" ::: "memory");          // buf[s&1] ready for all

        // ---- S^T = PhT . theta ----
        f32x4 sacc[4];
        #pragma unroll
        for (int i = 0; i < 4; ++i) sacc[i] = (f32x4){0.f, 0.f, 0.f, 0.f};
        #pragma unroll
        for (int kc = 0; kc < 4; ++kc) {
            #pragma unroll
            for (int msub = 0; msub < 4; ++msub) {
                int m = msub * 16 + col;
                int h = kc * 4 + quad;
                bf16x8 af = *(const bf16x8*)(smem + bb + ms * 16384 + m * 256 + ((h ^ (m & 15)) << 4));
                sacc[msub] = __builtin_amdgcn_mfma_f32_16x16x32_bf16(af, thf[kc], sacc[msub], 0, 0, 0);
            }
        }

        // ---- online softmax over m ----
        float tmax = sacc[0][0];
        #pragma unroll
        for (int i = 0; i < 4; ++i)
            #pragma unroll
            for (int r = 0; r < 4; ++r) tmax = fmaxf(tmax, sacc[i][r]);
        tmax = fmaxf(tmax, __shfl_xor(tmax, 16));
        tmax = fmaxf(tmax, __shfl_xor(tmax, 32));
        float m_new = fmaxf(m_st, tmax);
        float p16[16], ps = 0.f;
        #pragma unroll
        for (int i = 0; i < 4; ++i)
            #pragma unroll
            for (int r = 0; r < 4; ++r) {
                float pv = __expf(sacc[i][r] - m_new);
                p16[i * 4 + r] = pv;
                ps += pv;
            }
        ps += __shfl_xor(ps, 16);
        ps += __shfl_xor(ps, 32);
        float alpha = __expf(m_st - m_new);
        l_st = l_st * alpha + ps;
        m_st = m_new;
        #pragma unroll
        for (int i = 0; i < 8; ++i) {
            yacc[i][0] *= alpha; yacc[i][1] *= alpha;
            yacc[i][2] *= alpha; yacc[i][3] *= alpha;
        }

        // ---- pack P^T -> per-wave LDS ----
        {
            char* pb = smem + PB2 + w * 2048 + col * 128;
            #pragma unroll
            for (int msub = 0; msub < 4; ++msub) {
                #pragma unroll
                for (int pr = 0; pr < 2; ++pr) {
                    u32 d = packbf(p16[msub * 4 + pr * 2], p16[msub * 4 + pr * 2 + 1]);
                    int h = msub * 2 + (quad >> 1);
                    *(u32*)(pb + ((h ^ (col & 7)) << 4) + (quad & 1) * 8 + pr * 4) = d;
                }
            }
        }
        __asm volatile("s_waitcnt lgkmcnt(0)" ::: "memory");

        // ---- PV: y^T[c][q] += G . P^T ----
        bf16x8 pf[2];
        #pragma unroll
        for (int km = 0; km < 2; ++km) {
            int h = km * 4 + quad;
            pf[km] = *(const bf16x8*)(smem + PB2 + w * 2048 + col * 128 + ((h ^ (col & 7)) << 4));
        }
        #pragma unroll
        for (int csub = 0; csub < 8; ++csub) {
            #pragma unroll
            for (int km = 0; km < 2; ++km) {
                int c = csub * 16 + col;
                int h = km * 4 + quad;
                bf16x8 gf = *(const bf16x8*)(smem + 65536 + bb + ms * 16384 + c * 128 + ((h ^ (c & 7)) << 4));
                yacc[csub] = __builtin_amdgcn_mfma_f32_16x16x32_bf16(gf, pf[km], yacc[csub], 0, 0, 0);
            }
        }
    }

    // ---- merge m-parity partials; merged y -> LDS yB ----
    __syncthreads();
    if (ms == 1) {
        char* mb = smem + wq * 8192 + col * 512;
        #pragma unroll
        for (int csub = 0; csub < 8; ++csub)
            *(f32x4*)(mb + (((csub * 4 + quad) ^ col) << 4)) = yacc[csub];
        if (quad == 0) {
            *(float*)(smem + MST2 + (wq * 16 + col) * 4) = m_st;
            *(float*)(smem + LST2 + (wq * 16 + col) * 4) = l_st;
        }
    }
    __syncthreads();
    if (ms == 0) {
        float m1 = *(const float*)(smem + MST2 + (wq * 16 + col) * 4);
        float l1 = *(const float*)(smem + LST2 + (wq * 16 + col) * 4);
        float M  = fmaxf(m_st, m1);
        float a0 = __expf(m_st - M), a1 = __expf(m1 - M);
        float li = 1.f / (l_st * a0 + l1 * a1);
        float s0 = a0 * li, s1 = a1 * li;
        const char* mb = smem + wq * 8192 + col * 512;
        const int q = qw + col;
        #pragma unroll
        for (int csub = 0; csub < 8; ++csub) {
            f32x4 y1 = *(const f32x4*)(mb + (((csub * 4 + quad) ^ col) << 4));
            uint2 pv;
            pv.x = packbf(yacc[csub][0] * s0 + y1[0] * s1, yacc[csub][1] * s0 + y1[1] * s1);
            pv.y = packbf(yacc[csub][2] * s0 + y1[2] * s1, yacc[csub][3] * s0 + y1[3] * s1);
            int chunk = csub * 2 + (quad >> 1);
            *(uint2*)(smem + 32768 + q * 256 + ((chunk ^ (q & 15)) << 4) + (quad & 1) * 8) = pv;
        }
    }
    __syncthreads();

    // ---- fused outproj: W_y[o][q] = sum_c wo[o][c] * y[c][q] + bo ----
    const u16* wo = wbf + 98304;
    f32x4 oacc[2][4];
    #pragma unroll
    for (int i = 0; i < 2; ++i)
        #pragma unroll
        for (int j = 0; j < 4; ++j) oacc[i][j] = (f32x4){0.f,0.f,0.f,0.f};
    #pragma unroll
    for (int kc = 0; kc < 4; ++kc) {
        bf16x8 bqf[4];
        #pragma unroll
        for (int qf = 0; qf < 4; ++qf) {
            int q = qf * 16 + col;
            int h = kc * 4 + quad;
            bqf[qf] = *(const bf16x8*)(smem + 32768 + q * 256 + ((h ^ (q & 15)) << 4));
        }
        #pragma unroll
        for (int os = 0; os < 2; ++os) {
            bf16x8 afr = *(const bf16x8*)&wo[(size_t)(w * 32 + os * 16 + col) * CI_ + kc * 32 + quad * 8];
            #pragma unroll
            for (int qf = 0; qf < 4; ++qf)
                oacc[os][qf] = __builtin_amdgcn_mfma_f32_16x16x32_bf16(afr, bqf[qf], oacc[os][qf], 0, 0, 0);
        }
    }
    const int bucket = (blockIdx.x + blockIdx.y) & 7;
    float* sbk = stats + bucket * 512;
    #pragma unroll
    for (int os = 0; os < 2; ++os) {
        int ob = w * 32 + os * 16 + quad * 4;
        #pragma unroll
        for (int i = 0; i < 4; ++i) {
            float bb2 = canon[131456 + ob + i];
            float s1 = 0.f, s2 = 0.f;
            u16* dst = &wyb[((size_t)b * C_IN + ob + i) * N_TOK + q0 + col];
            #pragma unroll
            for (int qf = 0; qf < 4; ++qf) {
                float v = oacc[os][qf][i] + bb2;
                dst[qf * 16] = f2bf(v);
                s1 += v;
                s2 += v * v;
            }
            #pragma unroll
            for (int off = 8; off; off >>= 1) {
                s1 += __shfl_xor(s1, off);
                s2 += __shfl_xor(s2, off);
            }
            if (col == 0) {
                atomicAdd(&sbk[ob + i], s1);
                atomicAdd(&sbk[256 + ob + i], s2);
            }
        }
    }
}

// ===================== BN apply + residual =====================
__global__ __launch_bounds__(256) void bnorm_kernel(
    const u16* __restrict__ wyb, const void* __restrict__ x,
    const float* __restrict__ stats,
    const float* __restrict__ canon, const int* __restrict__ flagp,
    void* __restrict__ outv)
{
    const int flag = *flagp;
    size_t base = ((size_t)blockIdx.x * 256 + threadIdx.x) * 8;
    int o = (int)((base >> 12) & 255);
    float sum1 = 0.f, sum2 = 0.f;
    #pragma unroll
    for (int k = 0; k < 8; ++k) {
        sum1 += stats[k * 512 + o];
        sum2 += stats[k * 512 + 256 + o];
    }
    float mean = sum1 * (1.f / 16384.f);
    float var  = sum2 * (1.f / 16384.f) - mean * mean;
    float r = rsqrtf(var + 1e-5f);
    float gm = canon[131712 + o], bt = canon[131968 + o];
    uint4 wu = *(const uint4*)&wyb[base];
    float wv[8]; bf8f(wu, wv);
    float xf[8]; load8(x, base, flag, xf);
    float ov[8];
    #pragma unroll
    for (int i = 0; i < 8; ++i)
        ov[i] = (wv[i] - mean) * r * gm + bt + xf[i];
    if (flag) {
        float* op = (float*)outv + base;
        *(float4*)op       = *(float4*)&ov[0];
        *(float4*)(op + 4) = *(float4*)&ov[4];
    } else {
        uint4 res;
        res.x = packbf(ov[0], ov[1]);
        res.y = packbf(ov[2], ov[3]);
        res.z = packbf(ov[4], ov[5]);
        res.w = packbf(ov[6], ov[7]);
        *(uint4*)((u16*)outv + base) = res;
    }
}

extern "C" void kernel_launch(void* const* d_in, const int* in_sizes, int n_in,
                              void* d_out, int out_size, void* d_ws, size_t ws_size,
                              hipStream_t stream)
{
    const void* x   = d_in[0];
    const void* w_g = d_in[1];
    const void* b_g = d_in[2];
    const void* w_t = d_in[3];
    const void* b_t = d_in[4];
    const void* w_p = d_in[5];
    const void* b_p = d_in[6];
    const void* w_o = d_in[7];
    const void* b_o = d_in[8];
    const void* gm  = d_in[9];
    const void* bt  = d_in[10];

    char* base = (char*)d_ws;
    float* canon    = (float*)base;                    // 132224 f32
    u16*   canon_bf = (u16*)(base + 528896);           // 131072 u16
    int*   flagp    = (int*)(base + 791040);
    float* stats    = (float*)(base + 791296);         // 8 buckets x 512 f32
    u16*   gbuf     = (u16*)(base + 1048576);          // 4 MB bf16 [b][c][n]
    u16*   tbufT    = (u16*)(base + 5242880);          // 4 MB bf16 [b][n][c]
    u16*   pbufT    = (u16*)(base + 9437184);          // 4 MB bf16 [b][n][c]
    u16*   wyb      = (u16*)(base + 13631488);         // 8 MB bf16 [b][o][n]
    u16*   xbfT     = (u16*)(base + 22020096);         // 8 MB bf16 [b][n][k]

    convert_params_kernel<<<533, 256, 0, stream>>>(w_g, w_t, w_p, w_o, b_g, b_t, b_p, b_o,
                                                   gm, bt, flagp, canon, canon_bf, stats);
    xpose_kernel<<<dim3(64, 4, 4), 256, 0, stream>>>(x, flagp, xbfT);
    proj_kernel<<<dim3(64, 4), 512, 0, stream>>>(xbfT, canon, canon_bf, gbuf, tbufT, pbufT);
    attn_kernel<<<dim3(64, 4), 512, 0, stream>>>(tbufT, pbufT, gbuf, canon_bf, canon, wyb, stats);
    bnorm_kernel<<<2048, 256, 0, stream>>>(wyb, x, stats, canon, flagp, d_out);
}